// Round 2
// baseline (339.341 us; speedup 1.0000x reference)
//
#include <hip/hip_runtime.h>

// Attention_77730318123148 — B=2,S=2048,D=1024,H=16,HD=64. fp32 I/O, bf16 MFMA compute.
// Pipeline: cvt x/Wo -> bf16; cvt+transpose W{q,k,v}; NT GEMM QKV; flash attention;
// NT GEMM out-proj (fp32 out). All MFMA: v_mfma_f32_16x16x32_bf16, fp32 accum.

#define DD 1024
#define SS 2048
#define BB 2
#define HH 16
#define HD 64

typedef __attribute__((ext_vector_type(8))) short short8;   // 8 bf16 (A/B frag)
typedef __attribute__((ext_vector_type(4))) float float4v;  // C/D frag
typedef unsigned short ushort;
typedef unsigned int uint;

__device__ inline ushort f2bf(float f) {
    union { float f; uint i; } v; v.f = f;
    uint r = v.i + 0x7FFF + ((v.i >> 16) & 1);   // RNE
    return (ushort)(r >> 16);
}

// ---------------- elementwise fp32 -> bf16 (n4 = n/4 chunks) ----------------
__global__ __launch_bounds__(256) void cvt_bf16(const float* __restrict__ src,
                                                ushort* __restrict__ dst, int n4) {
    int i = blockIdx.x * 256 + threadIdx.x;
    if (i < n4) {
        float4 v = ((const float4*)src)[i];
        ushort o[4] = { f2bf(v.x), f2bf(v.y), f2bf(v.z), f2bf(v.w) };
        ((uint2*)dst)[i] = *(const uint2*)o;
    }
}

// ------------- W cvt+transpose: fp32 [H][D][HD] -> bf16 [H*HD][D] ------------
__global__ __launch_bounds__(256) void transpose_w(const float* __restrict__ W,
                                                   ushort* __restrict__ WT) {
    __shared__ ushort T[64][72];
    int h = blockIdx.y, d0 = blockIdx.x * 64;
    const float* Wh = W + h * DD * HD;
    ushort* Wt = WT + h * HD * DD;
    int t = threadIdx.x;
    #pragma unroll
    for (int i = 0; i < 4; i++) {
        int idx = t + i * 256;                 // 1024 chunks of 4 floats
        int d = idx >> 4, e4 = (idx & 15) * 4;
        float4 v = *(const float4*)(Wh + (d0 + d) * HD + e4);
        T[d][e4 + 0] = f2bf(v.x); T[d][e4 + 1] = f2bf(v.y);
        T[d][e4 + 2] = f2bf(v.z); T[d][e4 + 3] = f2bf(v.w);
    }
    __syncthreads();
    #pragma unroll
    for (int i = 0; i < 2; i++) {
        int idx = t + i * 256;                 // 512 chunks of 8 bf16
        int e = idx >> 3, d8 = (idx & 7) * 8;
        ushort tmp[8];
        #pragma unroll
        for (int j = 0; j < 8; j++) tmp[j] = T[d8 + j][e];
        *(uint4*)(Wt + e * DD + d0 + d8) = *(uint4*)tmp;
    }
}

// ---- QKV: xb[4096,1024] x WT[1024,1024]^T (NT) -> q/k/v bf16 [4096][1024] ----
__global__ __launch_bounds__(256) void gemm_qkv(const ushort* __restrict__ xb,
                                                const ushort* __restrict__ WqT,
                                                const ushort* __restrict__ WkT,
                                                const ushort* __restrict__ WvT,
                                                const float* __restrict__ bq,
                                                const float* __restrict__ bk,
                                                const float* __restrict__ bv,
                                                ushort* __restrict__ qb,
                                                ushort* __restrict__ kb,
                                                ushort* __restrict__ vb) {
    __shared__ ushort Al[64][40];
    __shared__ ushort Bl[64][40];
    int z = blockIdx.z;
    const ushort* Wt   = z == 0 ? WqT : (z == 1 ? WkT : WvT);
    const float*  bias = z == 0 ? bq  : (z == 1 ? bk  : bv);
    ushort* Out        = z == 0 ? qb  : (z == 1 ? kb  : vb);
    int m0 = blockIdx.x * 64, n0 = blockIdx.y * 64;
    int t = threadIdx.x, lane = t & 63, w = t >> 6;
    int qm = lane >> 4, lm = lane & 15;
    int sr = t >> 2, sc = (t & 3) * 8;

    float4v acc[4] = {};
    for (int k0 = 0; k0 < DD; k0 += 32) {
        __syncthreads();
        *(uint4*)(&Al[sr][sc]) = *(const uint4*)(xb + (m0 + sr) * DD + k0 + sc);
        *(uint4*)(&Bl[sr][sc]) = *(const uint4*)(Wt + (n0 + sr) * DD + k0 + sc);
        __syncthreads();
        short8 a = *(const short8*)(&Al[w * 16 + lm][qm * 8]);
        #pragma unroll
        for (int j = 0; j < 4; j++) {
            short8 b8 = *(const short8*)(&Bl[j * 16 + lm][qm * 8]);
            acc[j] = __builtin_amdgcn_mfma_f32_16x16x32_bf16(a, b8, acc[j], 0, 0, 0);
        }
    }
    // C/D: col = j*16+lm, row = w*16 + qm*4 + r
    #pragma unroll
    for (int j = 0; j < 4; j++) {
        float bb = bias[n0 + j * 16 + lm];
        #pragma unroll
        for (int r = 0; r < 4; r++) {
            int m = m0 + w * 16 + qm * 4 + r;
            Out[m * DD + n0 + j * 16 + lm] = f2bf(acc[j][r] + bb);
        }
    }
}

// -------- flash attention (causal); q/k/v layout [b*S+s][h*64+e] bf16 --------
__global__ __launch_bounds__(256) void attn(const ushort* __restrict__ Q,
                                            const ushort* __restrict__ K,
                                            const ushort* __restrict__ V,
                                            ushort* __restrict__ O) {
    __shared__ ushort Ql[64][72];
    __shared__ ushort Kl[64][72];
    __shared__ ushort Vl[64][68];
    __shared__ ushort Pl[4][16][72];
    int qt = blockIdx.x, bh = blockIdx.y;
    int b = bh >> 4, h = bh & 15;
    int m0 = qt * 64;
    const ushort* Qp = Q + (size_t)b * SS * DD + h * HD;   // row stride DD
    const ushort* Kp = K + (size_t)b * SS * DD + h * HD;
    const ushort* Vp = V + (size_t)b * SS * DD + h * HD;
    int t = threadIdx.x, lane = t & 63, w = t >> 6;
    int qm = lane >> 4, lm = lane & 15;

    #pragma unroll
    for (int i = 0; i < 2; i++) {
        int idx = t + i * 256;
        int r = idx >> 3, c8 = (idx & 7) * 8;
        *(uint4*)(&Ql[r][c8]) = *(const uint4*)(Qp + (m0 + r) * DD + c8);
    }

    float4v o[4] = {};
    float mi[4], li[4];
    #pragma unroll
    for (int r = 0; r < 4; r++) { mi[r] = -__builtin_inff(); li[r] = 0.f; }

    for (int jt = 0; jt <= qt; jt++) {
        int n0 = jt * 64;
        __syncthreads();   // prev compute done; also orders Q staging before 1st use
        #pragma unroll
        for (int i = 0; i < 2; i++) {
            int idx = t + i * 256;
            int r = idx >> 3, c8 = (idx & 7) * 8;
            *(uint4*)(&Kl[r][c8]) = *(const uint4*)(Kp + (n0 + r) * DD + c8);
        }
        #pragma unroll
        for (int i = 0; i < 4; i++) {
            int idx = t + i * 256;
            int r = idx >> 4, c4 = (idx & 15) * 4;
            *(uint2*)(&Vl[r][c4]) = *(const uint2*)(Vp + (n0 + r) * DD + c4);
        }
        __syncthreads();

        // S = Q K^T
        float4v s[4] = {};
        #pragma unroll
        for (int kc = 0; kc < 2; kc++) {
            short8 a = *(const short8*)(&Ql[w * 16 + lm][kc * 32 + qm * 8]);
            #pragma unroll
            for (int j = 0; j < 4; j++) {
                short8 b8 = *(const short8*)(&Kl[j * 16 + lm][kc * 32 + qm * 8]);
                s[j] = __builtin_amdgcn_mfma_f32_16x16x32_bf16(a, b8, s[j], 0, 0, 0);
            }
        }
        bool diag = (jt == qt);
        #pragma unroll
        for (int j = 0; j < 4; j++)
            #pragma unroll
            for (int r = 0; r < 4; r++) {
                float v_ = s[j][r] * 0.125f;
                if (diag) {
                    int mrel = w * 16 + qm * 4 + r;
                    int nrel = j * 16 + lm;
                    if (nrel > mrel) v_ = -__builtin_inff();
                }
                s[j][r] = v_;
            }
        float alpha[4];
        #pragma unroll
        for (int r = 0; r < 4; r++) {
            float mx = fmaxf(fmaxf(s[0][r], s[1][r]), fmaxf(s[2][r], s[3][r]));
            #pragma unroll
            for (int d = 1; d < 16; d <<= 1) mx = fmaxf(mx, __shfl_xor(mx, d, 64));
            float mnew = fmaxf(mi[r], mx);
            float sum = 0.f;
            #pragma unroll
            for (int j = 0; j < 4; j++) {
                float p = __expf(s[j][r] - mnew);
                s[j][r] = p;
                sum += p;
            }
            #pragma unroll
            for (int d = 1; d < 16; d <<= 1) sum += __shfl_xor(sum, d, 64);
            alpha[r] = __expf(mi[r] - mnew);
            li[r] = li[r] * alpha[r] + sum;
            mi[r] = mnew;
        }
        #pragma unroll
        for (int j = 0; j < 4; j++)
            #pragma unroll
            for (int r = 0; r < 4; r++) o[j][r] *= alpha[r];

        // P: C-layout -> A-layout via per-wave LDS round trip (m120 pattern)
        #pragma unroll
        for (int j = 0; j < 4; j++)
            #pragma unroll
            for (int r = 0; r < 4; r++)
                Pl[w][qm * 4 + r][j * 16 + lm] = f2bf(s[j][r]);
        asm volatile("s_waitcnt lgkmcnt(0)" ::: "memory");

        // O += P V
        #pragma unroll
        for (int kc = 0; kc < 2; kc++) {
            short8 a = *(const short8*)(&Pl[w][lm][kc * 32 + qm * 8]);
            #pragma unroll
            for (int jn = 0; jn < 4; jn++) {
                short8 b8;
                #pragma unroll
                for (int jj = 0; jj < 8; jj++)
                    b8[jj] = (short)Vl[kc * 32 + qm * 8 + jj][jn * 16 + lm];
                o[jn] = __builtin_amdgcn_mfma_f32_16x16x32_bf16(a, b8, o[jn], 0, 0, 0);
            }
        }
    }
    #pragma unroll
    for (int jn = 0; jn < 4; jn++)
        #pragma unroll
        for (int r = 0; r < 4; r++) {
            int sg = m0 + w * 16 + qm * 4 + r;
            O[((size_t)b * SS + sg) * DD + h * HD + jn * 16 + lm] = f2bf(o[jn][r] / li[r]);
        }
}

// ---- out proj: wvb[4096,1024] x Wob[1024,1024]^T (NT) + bo -> fp32 out ----
__global__ __launch_bounds__(256) void gemm_out(const ushort* __restrict__ X,
                                                const ushort* __restrict__ Wob,
                                                const float* __restrict__ bo,
                                                float* __restrict__ Out) {
    __shared__ ushort Al[64][40];
    __shared__ ushort Bl[64][40];
    int m0 = blockIdx.x * 64, n0 = blockIdx.y * 64;
    int t = threadIdx.x, lane = t & 63, w = t >> 6;
    int qm = lane >> 4, lm = lane & 15;
    int sr = t >> 2, sc = (t & 3) * 8;

    float4v acc[4] = {};
    for (int k0 = 0; k0 < DD; k0 += 32) {
        __syncthreads();
        *(uint4*)(&Al[sr][sc]) = *(const uint4*)(X + (m0 + sr) * DD + k0 + sc);
        *(uint4*)(&Bl[sr][sc]) = *(const uint4*)(Wob + (n0 + sr) * DD + k0 + sc);
        __syncthreads();
        short8 a = *(const short8*)(&Al[w * 16 + lm][qm * 8]);
        #pragma unroll
        for (int j = 0; j < 4; j++) {
            short8 b8 = *(const short8*)(&Bl[j * 16 + lm][qm * 8]);
            acc[j] = __builtin_amdgcn_mfma_f32_16x16x32_bf16(a, b8, acc[j], 0, 0, 0);
        }
    }
    #pragma unroll
    for (int j = 0; j < 4; j++) {
        float bb = bo[n0 + j * 16 + lm];
        #pragma unroll
        for (int r = 0; r < 4; r++) {
            int m = m0 + w * 16 + qm * 4 + r;
            Out[m * DD + n0 + j * 16 + lm] = acc[j][r] + bb;
        }
    }
}

extern "C" void kernel_launch(void* const* d_in, const int* in_sizes, int n_in,
                              void* d_out, int out_size, void* d_ws, size_t ws_size,
                              hipStream_t stream) {
    const float* x   = (const float*)d_in[0];
    const float* Wq  = (const float*)d_in[1];
    const float* bq  = (const float*)d_in[2];
    const float* Wk  = (const float*)d_in[3];
    const float* bk  = (const float*)d_in[4];
    const float* Wv_ = (const float*)d_in[5];
    const float* bv  = (const float*)d_in[6];
    const float* Wo  = (const float*)d_in[7];
    const float* bo  = (const float*)d_in[8];
    float* out = (float*)d_out;

    // workspace (bf16 elems): xb 4M | WqT/WkT/WvT 1M ea | Wob 1M | q/k/v 4M ea | wv 4M = 48 MB
    ushort* xb  = (ushort*)d_ws;
    ushort* WqT = xb  + (size_t)BB * SS * DD;
    ushort* WkT = WqT + (size_t)HH * HD * DD;
    ushort* WvT = WkT + (size_t)HH * HD * DD;
    ushort* Wob = WvT + (size_t)HH * HD * DD;
    ushort* qb  = Wob + (size_t)DD * DD;
    ushort* kb  = qb + (size_t)BB * SS * DD;
    ushort* vb  = kb + (size_t)BB * SS * DD;
    ushort* wvb = vb + (size_t)BB * SS * DD;

    cvt_bf16<<<dim3(4096), 256, 0, stream>>>(x, xb, (BB * SS * DD) / 4);
    cvt_bf16<<<dim3(1024), 256, 0, stream>>>(Wo, Wob, (DD * DD) / 4);
    transpose_w<<<dim3(16, 16), 256, 0, stream>>>(Wq, WqT);
    transpose_w<<<dim3(16, 16), 256, 0, stream>>>(Wk, WkT);
    transpose_w<<<dim3(16, 16), 256, 0, stream>>>(Wv_, WvT);
    gemm_qkv<<<dim3(64, 16, 3), 256, 0, stream>>>(xb, WqT, WkT, WvT, bq, bk, bv, qb, kb, vb);
    attn<<<dim3(32, 32), 256, 0, stream>>>(qb, kb, vb, wvb);
    gemm_out<<<dim3(64, 16), 256, 0, stream>>>(wvb, Wob, bo, out);
}

// Round 3
// 248.092 us; speedup vs baseline: 1.3678x; 1.3678x over previous
//
#include <hip/hip_runtime.h>

// Attention_77730318123148 — B=2,S=2048,D=1024,H=16,HD=64. fp32 I/O, bf16 MFMA compute.
// R3: m97-style 128x128 GEMMs (global_load_lds w=16); V pre-transposed so attn PV
// B-frags are ds_read_b128; causal pair-balancing (qt, 31-qt) per block.

#define DD 1024
#define SS 2048
#define BB 2
#define HH 16
#define HD 64

typedef __attribute__((ext_vector_type(8))) short short8;   // 8 bf16 (A/B frag)
typedef __attribute__((ext_vector_type(4))) float float4v;  // C/D frag
typedef unsigned short ushort;
typedef unsigned int uint;

__device__ inline ushort f2bf(float f) {
    union { float f; uint i; } v; v.f = f;
    uint r = v.i + 0x7FFF + ((v.i >> 16) & 1);   // RNE
    return (ushort)(r >> 16);
}

__device__ __forceinline__ void cp16(const ushort* g, ushort* l) {
    __builtin_amdgcn_global_load_lds((const __attribute__((address_space(1))) void*)g,
                                     (__attribute__((address_space(3))) void*)l,
                                     16, 0, 0);
}

// ---------------- elementwise fp32 -> bf16 (n4 = n/4 chunks) ----------------
__global__ __launch_bounds__(256) void cvt_bf16(const float* __restrict__ src,
                                                ushort* __restrict__ dst, int n4) {
    int i = blockIdx.x * 256 + threadIdx.x;
    if (i < n4) {
        float4 v = ((const float4*)src)[i];
        ushort o[4] = { f2bf(v.x), f2bf(v.y), f2bf(v.z), f2bf(v.w) };
        ((uint2*)dst)[i] = *(const uint2*)o;
    }
}

// ------------- W cvt+transpose: fp32 [H][D][HD] -> bf16 [H*HD][D] ------------
__global__ __launch_bounds__(256) void transpose_w(const float* __restrict__ W,
                                                   ushort* __restrict__ WT) {
    __shared__ ushort T[64][65];
    int h = blockIdx.y, d0 = blockIdx.x * 64;
    const float* Wh = W + h * DD * HD;
    ushort* Wt = WT + h * HD * DD;
    int t = threadIdx.x;
    #pragma unroll
    for (int i = 0; i < 4; i++) {
        int idx = t + i * 256;                 // 1024 chunks of 4 floats
        int d = idx >> 4, e4 = (idx & 15) * 4;
        float4 v = *(const float4*)(Wh + (d0 + d) * HD + e4);
        T[d][e4 + 0] = f2bf(v.x); T[d][e4 + 1] = f2bf(v.y);
        T[d][e4 + 2] = f2bf(v.z); T[d][e4 + 3] = f2bf(v.w);
    }
    __syncthreads();
    #pragma unroll
    for (int i = 0; i < 2; i++) {
        int idx = t + i * 256;                 // 512 chunks of 8 bf16
        int e = idx >> 3, d8 = (idx & 7) * 8;
        ushort tmp[8];
        #pragma unroll
        for (int j = 0; j < 8; j++) tmp[j] = T[d8 + j][e];
        *(uint4*)(Wt + e * DD + d0 + d8) = *(uint4*)tmp;
    }
}

// ---- V transpose: vb[b*S+s][h*64+e] -> vT[(bh*64+e)][s]  (bf16) ----
__global__ __launch_bounds__(256) void transpose_v(const ushort* __restrict__ vb,
                                                   ushort* __restrict__ vT) {
    __shared__ ushort T[64][65];
    int s0 = blockIdx.x * 64;
    int bh = blockIdx.y, b = bh >> 4, h = bh & 15;
    int t = threadIdx.x;
    #pragma unroll
    for (int i = 0; i < 2; i++) {
        int idx = t + i * 256;
        int r = idx >> 3, c8 = (idx & 7) * 8;
        uint4 v = *(const uint4*)(vb + (size_t)(b * SS + s0 + r) * DD + h * HD + c8);
        const ushort* pv = (const ushort*)&v;
        #pragma unroll
        for (int j = 0; j < 8; j++) T[r][c8 + j] = pv[j];
    }
    __syncthreads();
    #pragma unroll
    for (int i = 0; i < 2; i++) {
        int idx = t + i * 256;
        int e = idx >> 3, d8 = (idx & 7) * 8;
        ushort tmp[8];
        #pragma unroll
        for (int j = 0; j < 8; j++) tmp[j] = T[d8 + j][e];
        *(uint4*)(vT + (size_t)(bh * HD + e) * SS + s0 + d8) = *(uint4*)tmp;
    }
}

// ---- QKV: xb[4096,1024] x WT[1024,1024]^T (NT, 128x128 tile, global_load_lds) ----
__global__ __launch_bounds__(256) void gemm_qkv(const ushort* __restrict__ xb,
                                                const ushort* __restrict__ WqT,
                                                const ushort* __restrict__ WkT,
                                                const ushort* __restrict__ WvT,
                                                const float* __restrict__ bq,
                                                const float* __restrict__ bk,
                                                const float* __restrict__ bv,
                                                ushort* __restrict__ qb,
                                                ushort* __restrict__ kb,
                                                ushort* __restrict__ vb) {
    __shared__ ushort Al[128 * 32];
    __shared__ ushort Bl[128 * 32];
    int z = blockIdx.z;
    const ushort* Wt   = z == 0 ? WqT : (z == 1 ? WkT : WvT);
    const float*  bias = z == 0 ? bq  : (z == 1 ? bk  : bv);
    ushort* Out        = z == 0 ? qb  : (z == 1 ? kb  : vb);
    int m0 = blockIdx.x * 128, n0 = blockIdx.y * 128;
    int t = threadIdx.x, lane = t & 63, w = t >> 6;
    int wm = w & 1, wn = w >> 1;
    int qm = lane >> 4, lm = lane & 15;

    float4v acc[4][4] = {};
    for (int k0 = 0; k0 < DD; k0 += 32) {
        __syncthreads();
        #pragma unroll
        for (int r2 = 0; r2 < 2; r2++) {
            int c = t + r2 * 256;
            cp16(xb + (size_t)(m0 + (c >> 2)) * DD + k0 + (c & 3) * 8, Al + c * 8);
            cp16(Wt + (size_t)(n0 + (c >> 2)) * DD + k0 + (c & 3) * 8, Bl + c * 8);
        }
        __syncthreads();
        short8 a[4], b[4];
        #pragma unroll
        for (int i = 0; i < 4; i++)
            a[i] = *(const short8*)(Al + (wm * 64 + i * 16 + lm) * 32 + qm * 8);
        #pragma unroll
        for (int j = 0; j < 4; j++)
            b[j] = *(const short8*)(Bl + (wn * 64 + j * 16 + lm) * 32 + qm * 8);
        #pragma unroll
        for (int i = 0; i < 4; i++)
            #pragma unroll
            for (int j = 0; j < 4; j++)
                acc[i][j] = __builtin_amdgcn_mfma_f32_16x16x32_bf16(a[i], b[j], acc[i][j], 0, 0, 0);
    }
    #pragma unroll
    for (int j = 0; j < 4; j++) {
        int n = n0 + wn * 64 + j * 16 + lm;
        float bb = bias[n];
        #pragma unroll
        for (int i = 0; i < 4; i++)
            #pragma unroll
            for (int r = 0; r < 4; r++) {
                int m = m0 + wm * 64 + i * 16 + qm * 4 + r;
                Out[(size_t)m * DD + n] = f2bf(acc[i][j][r] + bb);
            }
    }
}

// -------- flash attention (causal); q/k [b*S+s][h*64+e], vT [(bh*64+e)][s] --------
// Block handles q-tile pair (px, 31-px): 33 tile-iters each -> perfect balance.
__global__ __launch_bounds__(256) void attn(const ushort* __restrict__ Q,
                                            const ushort* __restrict__ K,
                                            const ushort* __restrict__ VT,
                                            ushort* __restrict__ O) {
    __shared__ ushort Ql[64][72];
    __shared__ ushort Kl[64][72];
    __shared__ ushort Vt[64][72];      // [e][s_rel]
    __shared__ ushort Pl[4][16][72];
    int px = blockIdx.x, bh = blockIdx.y;
    int b = bh >> 4, h = bh & 15;
    const ushort* Qp = Q + (size_t)b * SS * DD + h * HD;
    const ushort* Kp = K + (size_t)b * SS * DD + h * HD;
    const ushort* Vp = VT + (size_t)bh * HD * SS;
    int t = threadIdx.x, lane = t & 63, w = t >> 6;
    int qm = lane >> 4, lm = lane & 15;

    #pragma unroll
    for (int ph = 0; ph < 2; ph++) {
        int qt = ph == 0 ? px : 31 - px;
        int m0 = qt * 64;
        __syncthreads();   // prior phase's reads of Ql done
        #pragma unroll
        for (int i = 0; i < 2; i++) {
            int idx = t + i * 256;
            int r = idx >> 3, c8 = (idx & 7) * 8;
            *(uint4*)(&Ql[r][c8]) = *(const uint4*)(Qp + (size_t)(m0 + r) * DD + c8);
        }

        float4v o[4] = {};
        float mi[4], li[4];
        #pragma unroll
        for (int r = 0; r < 4; r++) { mi[r] = -__builtin_inff(); li[r] = 0.f; }

        for (int jt = 0; jt <= qt; jt++) {
            int n0 = jt * 64;
            __syncthreads();   // prev compute done before restaging K/Vt (orders Ql too)
            #pragma unroll
            for (int i = 0; i < 2; i++) {
                int idx = t + i * 256;
                int r = idx >> 3, c8 = (idx & 7) * 8;
                *(uint4*)(&Kl[r][c8]) = *(const uint4*)(Kp + (size_t)(n0 + r) * DD + c8);
                *(uint4*)(&Vt[r][c8]) = *(const uint4*)(Vp + (size_t)r * SS + n0 + c8);
            }
            __syncthreads();

            // S = Q K^T
            float4v s[4] = {};
            #pragma unroll
            for (int kc = 0; kc < 2; kc++) {
                short8 a = *(const short8*)(&Ql[w * 16 + lm][kc * 32 + qm * 8]);
                #pragma unroll
                for (int j = 0; j < 4; j++) {
                    short8 b8 = *(const short8*)(&Kl[j * 16 + lm][kc * 32 + qm * 8]);
                    s[j] = __builtin_amdgcn_mfma_f32_16x16x32_bf16(a, b8, s[j], 0, 0, 0);
                }
            }
            bool diag = (jt == qt);
            #pragma unroll
            for (int j = 0; j < 4; j++)
                #pragma unroll
                for (int r = 0; r < 4; r++) {
                    float v_ = s[j][r] * 0.125f;
                    if (diag) {
                        int mrel = w * 16 + qm * 4 + r;
                        int nrel = j * 16 + lm;
                        if (nrel > mrel) v_ = -__builtin_inff();
                    }
                    s[j][r] = v_;
                }
            float alpha[4];
            #pragma unroll
            for (int r = 0; r < 4; r++) {
                float mx = fmaxf(fmaxf(s[0][r], s[1][r]), fmaxf(s[2][r], s[3][r]));
                #pragma unroll
                for (int d = 1; d < 16; d <<= 1) mx = fmaxf(mx, __shfl_xor(mx, d, 64));
                float mnew = fmaxf(mi[r], mx);
                float sum = 0.f;
                #pragma unroll
                for (int j = 0; j < 4; j++) {
                    float p = __expf(s[j][r] - mnew);
                    s[j][r] = p;
                    sum += p;
                }
                #pragma unroll
                for (int d = 1; d < 16; d <<= 1) sum += __shfl_xor(sum, d, 64);
                alpha[r] = __expf(mi[r] - mnew);
                li[r] = li[r] * alpha[r] + sum;
                mi[r] = mnew;
            }
            #pragma unroll
            for (int j = 0; j < 4; j++)
                #pragma unroll
                for (int r = 0; r < 4; r++) o[j][r] *= alpha[r];

            // P: C-layout -> A-layout via per-wave LDS round trip
            #pragma unroll
            for (int j = 0; j < 4; j++)
                #pragma unroll
                for (int r = 0; r < 4; r++)
                    Pl[w][qm * 4 + r][j * 16 + lm] = f2bf(s[j][r]);
            asm volatile("s_waitcnt lgkmcnt(0)" ::: "memory");  // wave-internal RAW

            // O += P V   (B frag = Vt[n=e][k=s_rel], contiguous b128)
            #pragma unroll
            for (int kc = 0; kc < 2; kc++) {
                short8 a = *(const short8*)(&Pl[w][lm][kc * 32 + qm * 8]);
                #pragma unroll
                for (int jn = 0; jn < 4; jn++) {
                    short8 b8 = *(const short8*)(&Vt[jn * 16 + lm][kc * 32 + qm * 8]);
                    o[jn] = __builtin_amdgcn_mfma_f32_16x16x32_bf16(a, b8, o[jn], 0, 0, 0);
                }
            }
        }
        #pragma unroll
        for (int jn = 0; jn < 4; jn++)
            #pragma unroll
            for (int r = 0; r < 4; r++) {
                int sg = m0 + w * 16 + qm * 4 + r;
                O[((size_t)b * SS + sg) * DD + h * HD + jn * 16 + lm] = f2bf(o[jn][r] / li[r]);
            }
    }
}

// ---- out proj: wvb[4096,1024] x Wob^T (NT, 128x128, global_load_lds) -> fp32 ----
__global__ __launch_bounds__(256) void gemm_out(const ushort* __restrict__ X,
                                                const ushort* __restrict__ Wob,
                                                const float* __restrict__ bo,
                                                float* __restrict__ Out) {
    __shared__ ushort Al[128 * 32];
    __shared__ ushort Bl[128 * 32];
    int m0 = blockIdx.x * 128, n0 = blockIdx.y * 128;
    int t = threadIdx.x, lane = t & 63, w = t >> 6;
    int wm = w & 1, wn = w >> 1;
    int qm = lane >> 4, lm = lane & 15;

    float4v acc[4][4] = {};
    for (int k0 = 0; k0 < DD; k0 += 32) {
        __syncthreads();
        #pragma unroll
        for (int r2 = 0; r2 < 2; r2++) {
            int c = t + r2 * 256;
            cp16(X   + (size_t)(m0 + (c >> 2)) * DD + k0 + (c & 3) * 8, Al + c * 8);
            cp16(Wob + (size_t)(n0 + (c >> 2)) * DD + k0 + (c & 3) * 8, Bl + c * 8);
        }
        __syncthreads();
        short8 a[4], b[4];
        #pragma unroll
        for (int i = 0; i < 4; i++)
            a[i] = *(const short8*)(Al + (wm * 64 + i * 16 + lm) * 32 + qm * 8);
        #pragma unroll
        for (int j = 0; j < 4; j++)
            b[j] = *(const short8*)(Bl + (wn * 64 + j * 16 + lm) * 32 + qm * 8);
        #pragma unroll
        for (int i = 0; i < 4; i++)
            #pragma unroll
            for (int j = 0; j < 4; j++)
                acc[i][j] = __builtin_amdgcn_mfma_f32_16x16x32_bf16(a[i], b[j], acc[i][j], 0, 0, 0);
    }
    #pragma unroll
    for (int j = 0; j < 4; j++) {
        int n = n0 + wn * 64 + j * 16 + lm;
        float bb = bo[n];
        #pragma unroll
        for (int i = 0; i < 4; i++)
            #pragma unroll
            for (int r = 0; r < 4; r++) {
                int m = m0 + wm * 64 + i * 16 + qm * 4 + r;
                Out[(size_t)m * DD + n] = acc[i][j][r] + bb;
            }
    }
}

extern "C" void kernel_launch(void* const* d_in, const int* in_sizes, int n_in,
                              void* d_out, int out_size, void* d_ws, size_t ws_size,
                              hipStream_t stream) {
    const float* x   = (const float*)d_in[0];
    const float* Wq  = (const float*)d_in[1];
    const float* bq  = (const float*)d_in[2];
    const float* Wk  = (const float*)d_in[3];
    const float* bk  = (const float*)d_in[4];
    const float* Wv_ = (const float*)d_in[5];
    const float* bv  = (const float*)d_in[6];
    const float* Wo  = (const float*)d_in[7];
    const float* bo  = (const float*)d_in[8];
    float* out = (float*)d_out;

    // workspace (bf16 elems): xb 4M | WqT/WkT/WvT/Wob 1M ea | q/k/v 4M ea | vT 4M | wv 4M = 56 MB
    ushort* xb  = (ushort*)d_ws;
    ushort* WqT = xb  + (size_t)BB * SS * DD;
    ushort* WkT = WqT + (size_t)HH * HD * DD;
    ushort* WvT = WkT + (size_t)HH * HD * DD;
    ushort* Wob = WvT + (size_t)HH * HD * DD;
    ushort* qb  = Wob + (size_t)DD * DD;
    ushort* kb  = qb + (size_t)BB * SS * DD;
    ushort* vb  = kb + (size_t)BB * SS * DD;
    ushort* vT  = vb + (size_t)BB * SS * DD;
    ushort* wvb = vT + (size_t)BB * SS * DD;

    cvt_bf16<<<dim3(4096), 256, 0, stream>>>(x, xb, (BB * SS * DD) / 4);
    cvt_bf16<<<dim3(1024), 256, 0, stream>>>(Wo, Wob, (DD * DD) / 4);
    transpose_w<<<dim3(16, 16), 256, 0, stream>>>(Wq, WqT);
    transpose_w<<<dim3(16, 16), 256, 0, stream>>>(Wk, WkT);
    transpose_w<<<dim3(16, 16), 256, 0, stream>>>(Wv_, WvT);
    gemm_qkv<<<dim3(32, 8, 3), 256, 0, stream>>>(xb, WqT, WkT, WvT, bq, bk, bv, qb, kb, vb);
    transpose_v<<<dim3(32, 32), 256, 0, stream>>>(vb, vT);
    attn<<<dim3(16, 32), 256, 0, stream>>>(qb, kb, vT, wvb);
    gemm_out<<<dim3(32, 8), 256, 0, stream>>>(wvb, Wob, bo, out);
}

// Round 4
// 230.528 us; speedup vs baseline: 1.4720x; 1.0762x over previous
//
#include <hip/hip_runtime.h>

// Attention_77730318123148 — B=2,S=2048,D=1024,H=16,HD=64. fp32 I/O, bf16 MFMA compute.
// R4: attn K/V double-buffer (1 barrier/iter) + reg prefetch; Q prescaled by 0.125*log2e
// in gemm_qkv epilogue (softmax in exp2 domain); V-transpose fused into gemm_qkv z==2;
// merged cvt/transpose launches. 5 kernels total.

#define DD 1024
#define SS 2048
#define BB 2
#define HH 16
#define HD 64
#define QSCALE 0.18033688011112042f   // 0.125 * log2(e)

typedef __attribute__((ext_vector_type(8))) short short8;   // 8 bf16 (A/B frag)
typedef __attribute__((ext_vector_type(4))) float float4v;  // C/D frag
typedef unsigned short ushort;
typedef unsigned int uint;

__device__ inline ushort f2bf(float f) {       // RNE (input conversion fidelity)
    union { float f; uint i; } v; v.f = f;
    uint r = v.i + 0x7FFF + ((v.i >> 16) & 1);
    return (ushort)(r >> 16);
}
__device__ inline ushort f2bf_f(float f) {     // round-half-up, 2 ops (hot paths)
    union { float f; uint i; } v; v.f = f;
    return (ushort)((v.i + 0x8000u) >> 16);
}

__device__ __forceinline__ void cp16(const ushort* g, ushort* l) {
    __builtin_amdgcn_global_load_lds((const __attribute__((address_space(1))) void*)g,
                                     (__attribute__((address_space(3))) void*)l,
                                     16, 0, 0);
}

// ---------- merged fp32->bf16 convert: x (1048576 chunks) then Wo (262144) ----------
__global__ __launch_bounds__(256) void cvt_all(const float* __restrict__ x,
                                               const float* __restrict__ Wo,
                                               ushort* __restrict__ xb,
                                               ushort* __restrict__ Wob) {
    const int NX4 = (BB * SS * DD) / 4;
    int i = blockIdx.x * 256 + threadIdx.x;
    const float* src; ushort* dst; int j;
    if (i < NX4) { src = x; dst = xb; j = i; }
    else         { src = Wo; dst = Wob; j = i - NX4; }
    float4 v = ((const float4*)src)[j];
    ushort o[4] = { f2bf(v.x), f2bf(v.y), f2bf(v.z), f2bf(v.w) };
    ((uint2*)dst)[j] = *(const uint2*)o;
}

// ------- W cvt+transpose: fp32 [H][D][HD] -> bf16 W3T[(z*16+h)*64+e][d], z over q/k/v -------
__global__ __launch_bounds__(256) void transpose_w3(const float* __restrict__ Wq,
                                                    const float* __restrict__ Wk,
                                                    const float* __restrict__ Wv,
                                                    ushort* __restrict__ W3T) {
    __shared__ ushort T[64][65];
    int z = blockIdx.z;
    const float* W = z == 0 ? Wq : (z == 1 ? Wk : Wv);
    int h = blockIdx.y, d0 = blockIdx.x * 64;
    const float* Wh = W + h * DD * HD;
    ushort* Wt = W3T + ((size_t)z * HH + h) * HD * DD;
    int t = threadIdx.x;
    #pragma unroll
    for (int i = 0; i < 4; i++) {
        int idx = t + i * 256;
        int d = idx >> 4, e4 = (idx & 15) * 4;
        float4 v = *(const float4*)(Wh + (d0 + d) * HD + e4);
        T[d][e4 + 0] = f2bf(v.x); T[d][e4 + 1] = f2bf(v.y);
        T[d][e4 + 2] = f2bf(v.z); T[d][e4 + 3] = f2bf(v.w);
    }
    __syncthreads();
    #pragma unroll
    for (int i = 0; i < 2; i++) {
        int idx = t + i * 256;
        int e = idx >> 3, d8 = (idx & 7) * 8;
        ushort tmp[8];
        #pragma unroll
        for (int j = 0; j < 8; j++) tmp[j] = T[d8 + j][e];
        *(uint4*)(Wt + e * DD + d0 + d8) = *(uint4*)tmp;
    }
}

// ---- QKV: xb[4096,1024] x W3T slice (NT, 128x128, global_load_lds). z=0: Q prescaled;
// ---- z=2: writes V transposed vT[(bh*64+e)][s] directly (8B stores along s).
__global__ __launch_bounds__(256) void gemm_qkv(const ushort* __restrict__ xb,
                                                const ushort* __restrict__ W3T,
                                                const float* __restrict__ bq,
                                                const float* __restrict__ bk,
                                                const float* __restrict__ bv,
                                                ushort* __restrict__ qb,
                                                ushort* __restrict__ kb,
                                                ushort* __restrict__ vT) {
    __shared__ ushort Al[128 * 32];
    __shared__ ushort Bl[128 * 32];
    int z = blockIdx.z;
    const ushort* Wt   = W3T + (size_t)z * HH * HD * DD;
    const float*  bias = z == 0 ? bq : (z == 1 ? bk : bv);
    int m0 = blockIdx.x * 128, n0 = blockIdx.y * 128;
    int t = threadIdx.x, lane = t & 63, w = t >> 6;
    int wm = w & 1, wn = w >> 1;
    int qm = lane >> 4, lm = lane & 15;

    float4v acc[4][4] = {};
    for (int k0 = 0; k0 < DD; k0 += 32) {
        __syncthreads();
        #pragma unroll
        for (int r2 = 0; r2 < 2; r2++) {
            int c = t + r2 * 256;
            cp16(xb + (size_t)(m0 + (c >> 2)) * DD + k0 + (c & 3) * 8, Al + c * 8);
            cp16(Wt + (size_t)(n0 + (c >> 2)) * DD + k0 + (c & 3) * 8, Bl + c * 8);
        }
        __syncthreads();
        short8 a[4], b[4];
        #pragma unroll
        for (int i = 0; i < 4; i++)
            a[i] = *(const short8*)(Al + (wm * 64 + i * 16 + lm) * 32 + qm * 8);
        #pragma unroll
        for (int j = 0; j < 4; j++)
            b[j] = *(const short8*)(Bl + (wn * 64 + j * 16 + lm) * 32 + qm * 8);
        #pragma unroll
        for (int i = 0; i < 4; i++)
            #pragma unroll
            for (int j = 0; j < 4; j++)
                acc[i][j] = __builtin_amdgcn_mfma_f32_16x16x32_bf16(a[i], b[j], acc[i][j], 0, 0, 0);
    }
    if (z == 2) {
        // transposed V: vT[((b*HH+h)*HD+e)][s], 4 consecutive s per (i,j) -> uint2 store
        #pragma unroll
        for (int j = 0; j < 4; j++) {
            int n = n0 + wn * 64 + j * 16 + lm;
            int h = n >> 6, e = n & 63;
            float bb = bias[n];
            #pragma unroll
            for (int i = 0; i < 4; i++) {
                int m = m0 + wm * 64 + i * 16 + qm * 4;
                int b_ = m >> 11, s = m & (SS - 1);
                ushort p4[4];
                #pragma unroll
                for (int r = 0; r < 4; r++) p4[r] = f2bf_f(acc[i][j][r] + bb);
                *(uint2*)(vT + ((size_t)(b_ * HH + h) * HD + e) * SS + s) = *(const uint2*)p4;
            }
        }
    } else {
        ushort* Out = z == 0 ? qb : kb;
        float sc = z == 0 ? QSCALE : 1.0f;
        #pragma unroll
        for (int j = 0; j < 4; j++) {
            int n = n0 + wn * 64 + j * 16 + lm;
            float bb = bias[n];
            #pragma unroll
            for (int i = 0; i < 4; i++)
                #pragma unroll
                for (int r = 0; r < 4; r++) {
                    int m = m0 + wm * 64 + i * 16 + qm * 4 + r;
                    Out[(size_t)m * DD + n] = f2bf_f((acc[i][j][r] + bb) * sc);
                }
        }
    }
}

// -------- flash attention (causal); q/k [b*S+s][h*64+e] (q prescaled), vT [(bh*64+e)][s] --------
// Pair-balanced (qt, 31-qt): 33 tile-iters/block. K/V double-buffered, 1 barrier/iter.
__global__ __launch_bounds__(256) void attn(const ushort* __restrict__ Q,
                                            const ushort* __restrict__ K,
                                            const ushort* __restrict__ VT,
                                            ushort* __restrict__ O) {
    __shared__ ushort Ql[64][72];
    __shared__ ushort Kl[2][64][72];
    __shared__ ushort Vl[2][64][72];
    __shared__ ushort Pl[4][16][72];
    int px = blockIdx.x, bh = blockIdx.y;
    int b = bh >> 4, h = bh & 15;
    const ushort* Qp = Q + (size_t)b * SS * DD + h * HD;
    const ushort* Kp = K + (size_t)b * SS * DD + h * HD;
    const ushort* Vp = VT + (size_t)bh * HD * SS;
    int t = threadIdx.x, lane = t & 63, w = t >> 6;
    int qm = lane >> 4, lm = lane & 15;
    int row0 = t >> 3, colc = (t & 7) * 8;   // staging: rows row0, row0+32

    #pragma unroll
    for (int ph = 0; ph < 2; ph++) {
        int qt = ph ? 31 - px : px;
        int m0 = qt * 64;
        __syncthreads();   // prior phase fully done with all LDS
        *(uint4*)(&Ql[row0][colc])      = *(const uint4*)(Qp + (size_t)(m0 + row0) * DD + colc);
        *(uint4*)(&Ql[row0 + 32][colc]) = *(const uint4*)(Qp + (size_t)(m0 + row0 + 32) * DD + colc);
        *(uint4*)(&Kl[0][row0][colc])      = *(const uint4*)(Kp + (size_t)row0 * DD + colc);
        *(uint4*)(&Kl[0][row0 + 32][colc]) = *(const uint4*)(Kp + (size_t)(row0 + 32) * DD + colc);
        *(uint4*)(&Vl[0][row0][colc])      = *(const uint4*)(Vp + (size_t)row0 * SS + colc);
        *(uint4*)(&Vl[0][row0 + 32][colc]) = *(const uint4*)(Vp + (size_t)(row0 + 32) * SS + colc);

        float4v o[4] = {};
        float mi[4], li[4];
        #pragma unroll
        for (int r = 0; r < 4; r++) { mi[r] = -__builtin_inff(); li[r] = 0.f; }
        int cur = 0;

        for (int jt = 0; jt <= qt; jt++) {
            __syncthreads();   // cur buf staged+visible; prev iter's reads of cur^1 done
            bool pre = jt < qt;
            uint4 pk0, pk1, pv0, pv1;
            if (pre) {
                int nn = (jt + 1) * 64;
                pk0 = *(const uint4*)(Kp + (size_t)(nn + row0) * DD + colc);
                pk1 = *(const uint4*)(Kp + (size_t)(nn + row0 + 32) * DD + colc);
                pv0 = *(const uint4*)(Vp + (size_t)row0 * SS + nn + colc);
                pv1 = *(const uint4*)(Vp + (size_t)(row0 + 32) * SS + nn + colc);
            }

            // S = Q K^T  (q prescaled by 0.125*log2e -> softmax in exp2 domain)
            float4v s[4] = {};
            #pragma unroll
            for (int kc = 0; kc < 2; kc++) {
                short8 a = *(const short8*)(&Ql[w * 16 + lm][kc * 32 + qm * 8]);
                #pragma unroll
                for (int j = 0; j < 4; j++) {
                    short8 b8 = *(const short8*)(&Kl[cur][j * 16 + lm][kc * 32 + qm * 8]);
                    s[j] = __builtin_amdgcn_mfma_f32_16x16x32_bf16(a, b8, s[j], 0, 0, 0);
                }
            }
            if (jt == qt) {   // diagonal causal mask
                #pragma unroll
                for (int j = 0; j < 4; j++)
                    #pragma unroll
                    for (int r = 0; r < 4; r++) {
                        int mrel = w * 16 + qm * 4 + r;
                        int nrel = j * 16 + lm;
                        if (nrel > mrel) s[j][r] = -__builtin_inff();
                    }
            }
            float alpha[4];
            #pragma unroll
            for (int r = 0; r < 4; r++) {
                float mx = fmaxf(fmaxf(s[0][r], s[1][r]), fmaxf(s[2][r], s[3][r]));
                #pragma unroll
                for (int d = 1; d < 16; d <<= 1) mx = fmaxf(mx, __shfl_xor(mx, d, 64));
                float mnew = fmaxf(mi[r], mx);
                float p0 = __builtin_amdgcn_exp2f(s[0][r] - mnew);
                float p1 = __builtin_amdgcn_exp2f(s[1][r] - mnew);
                float p2 = __builtin_amdgcn_exp2f(s[2][r] - mnew);
                float p3 = __builtin_amdgcn_exp2f(s[3][r] - mnew);
                s[0][r] = p0; s[1][r] = p1; s[2][r] = p2; s[3][r] = p3;
                float sum = (p0 + p1) + (p2 + p3);
                #pragma unroll
                for (int d = 1; d < 16; d <<= 1) sum += __shfl_xor(sum, d, 64);
                alpha[r] = __builtin_amdgcn_exp2f(mi[r] - mnew);
                li[r] = li[r] * alpha[r] + sum;
                mi[r] = mnew;
            }
            #pragma unroll
            for (int j = 0; j < 4; j++)
                #pragma unroll
                for (int r = 0; r < 4; r++) o[j][r] *= alpha[r];

            // P: C-layout -> A-layout via per-wave LDS round trip
            #pragma unroll
            for (int j = 0; j < 4; j++)
                #pragma unroll
                for (int r = 0; r < 4; r++)
                    Pl[w][qm * 4 + r][j * 16 + lm] = f2bf_f(s[j][r]);
            asm volatile("s_waitcnt lgkmcnt(0)" ::: "memory");   // wave-internal RAW

            // O += P V
            #pragma unroll
            for (int kc = 0; kc < 2; kc++) {
                short8 a = *(const short8*)(&Pl[w][lm][kc * 32 + qm * 8]);
                #pragma unroll
                for (int jn = 0; jn < 4; jn++) {
                    short8 b8 = *(const short8*)(&Vl[cur][jn * 16 + lm][kc * 32 + qm * 8]);
                    o[jn] = __builtin_amdgcn_mfma_f32_16x16x32_bf16(a, b8, o[jn], 0, 0, 0);
                }
            }
            if (pre) {   // write prefetched tile into the other buffer
                *(uint4*)(&Kl[cur ^ 1][row0][colc])      = pk0;
                *(uint4*)(&Kl[cur ^ 1][row0 + 32][colc]) = pk1;
                *(uint4*)(&Vl[cur ^ 1][row0][colc])      = pv0;
                *(uint4*)(&Vl[cur ^ 1][row0 + 32][colc]) = pv1;
            }
            cur ^= 1;
        }
        #pragma unroll
        for (int jn = 0; jn < 4; jn++)
            #pragma unroll
            for (int r = 0; r < 4; r++) {
                int sg = m0 + w * 16 + qm * 4 + r;
                O[((size_t)b * SS + sg) * DD + h * HD + jn * 16 + lm] = f2bf_f(o[jn][r] / li[r]);
            }
    }
}

// ---- out proj: wvb[4096,1024] x Wob^T (NT, 128x128, global_load_lds) -> fp32 ----
__global__ __launch_bounds__(256) void gemm_out(const ushort* __restrict__ X,
                                                const ushort* __restrict__ Wob,
                                                const float* __restrict__ bo,
                                                float* __restrict__ Out) {
    __shared__ ushort Al[128 * 32];
    __shared__ ushort Bl[128 * 32];
    int m0 = blockIdx.x * 128, n0 = blockIdx.y * 128;
    int t = threadIdx.x, lane = t & 63, w = t >> 6;
    int wm = w & 1, wn = w >> 1;
    int qm = lane >> 4, lm = lane & 15;

    float4v acc[4][4] = {};
    for (int k0 = 0; k0 < DD; k0 += 32) {
        __syncthreads();
        #pragma unroll
        for (int r2 = 0; r2 < 2; r2++) {
            int c = t + r2 * 256;
            cp16(X   + (size_t)(m0 + (c >> 2)) * DD + k0 + (c & 3) * 8, Al + c * 8);
            cp16(Wob + (size_t)(n0 + (c >> 2)) * DD + k0 + (c & 3) * 8, Bl + c * 8);
        }
        __syncthreads();
        short8 a[4], b[4];
        #pragma unroll
        for (int i = 0; i < 4; i++)
            a[i] = *(const short8*)(Al + (wm * 64 + i * 16 + lm) * 32 + qm * 8);
        #pragma unroll
        for (int j = 0; j < 4; j++)
            b[j] = *(const short8*)(Bl + (wn * 64 + j * 16 + lm) * 32 + qm * 8);
        #pragma unroll
        for (int i = 0; i < 4; i++)
            #pragma unroll
            for (int j = 0; j < 4; j++)
                acc[i][j] = __builtin_amdgcn_mfma_f32_16x16x32_bf16(a[i], b[j], acc[i][j], 0, 0, 0);
    }
    #pragma unroll
    for (int j = 0; j < 4; j++) {
        int n = n0 + wn * 64 + j * 16 + lm;
        float bb = bo[n];
        #pragma unroll
        for (int i = 0; i < 4; i++)
            #pragma unroll
            for (int r = 0; r < 4; r++) {
                int m = m0 + wm * 64 + i * 16 + qm * 4 + r;
                Out[(size_t)m * DD + n] = acc[i][j][r] + bb;
            }
    }
}

extern "C" void kernel_launch(void* const* d_in, const int* in_sizes, int n_in,
                              void* d_out, int out_size, void* d_ws, size_t ws_size,
                              hipStream_t stream) {
    const float* x   = (const float*)d_in[0];
    const float* Wq  = (const float*)d_in[1];
    const float* bq  = (const float*)d_in[2];
    const float* Wk  = (const float*)d_in[3];
    const float* bk  = (const float*)d_in[4];
    const float* Wv_ = (const float*)d_in[5];
    const float* bv  = (const float*)d_in[6];
    const float* Wo  = (const float*)d_in[7];
    const float* bo  = (const float*)d_in[8];
    float* out = (float*)d_out;

    // workspace (bf16 elems): xb 4M | W3T 3M | Wob 1M | qb/kb 4M ea | vT 4M | wvb 4M = 48 MB
    ushort* xb  = (ushort*)d_ws;
    ushort* W3T = xb  + (size_t)BB * SS * DD;
    ushort* Wob = W3T + (size_t)3 * HH * HD * DD;
    ushort* qb  = Wob + (size_t)DD * DD;
    ushort* kb  = qb + (size_t)BB * SS * DD;
    ushort* vT  = kb + (size_t)BB * SS * DD;
    ushort* wvb = vT + (size_t)BB * SS * DD;

    cvt_all<<<dim3(5120), 256, 0, stream>>>(x, Wo, xb, Wob);
    transpose_w3<<<dim3(16, 16, 3), 256, 0, stream>>>(Wq, Wk, Wv_, W3T);
    gemm_qkv<<<dim3(32, 8, 3), 256, 0, stream>>>(xb, W3T, bq, bk, bv, qb, kb, vT);
    attn<<<dim3(16, 32), 256, 0, stream>>>(qb, kb, vT, wvb);
    gemm_out<<<dim3(32, 8), 256, 0, stream>>>(wvb, Wob, bo, out);
}

// Round 5
// 204.629 us; speedup vs baseline: 1.6583x; 1.1266x over previous
//
#include <hip/hip_runtime.h>

// Attention_77730318123148 — B=2,S=2048,D=1024,H=16,HD=64. fp32 I/O, bf16 MFMA compute.
// R5: attn computes S^T = K·Q^T so each softmax row is in-lane (2 shfl reductions,
// b64 P writes, b128 P reads); 512-thr blocks, q-tile 128, paired; LDS stride 88
// (bank-spread); gemm_out 128x64 tiles.

#define DD 1024
#define SS 2048
#define BB 2
#define HH 16
#define HD 64
#define QSCALE 0.18033688011112042f   // 0.125 * log2(e)
#define LSTR 88                        // LDS row stride (ushorts): 176B, 16B-aligned, bank-spread

typedef __attribute__((ext_vector_type(8))) short short8;   // 8 bf16 (A/B frag)
typedef __attribute__((ext_vector_type(4))) float float4v;  // C/D frag
typedef unsigned short ushort;
typedef unsigned int uint;

__device__ inline ushort f2bf(float f) {       // RNE (input conversion fidelity)
    union { float f; uint i; } v; v.f = f;
    uint r = v.i + 0x7FFF + ((v.i >> 16) & 1);
    return (ushort)(r >> 16);
}
__device__ inline ushort f2bf_f(float f) {     // round-half-up, 2 ops (hot paths)
    union { float f; uint i; } v; v.f = f;
    return (ushort)((v.i + 0x8000u) >> 16);
}

__device__ __forceinline__ void cp16(const ushort* g, ushort* l) {
    __builtin_amdgcn_global_load_lds((const __attribute__((address_space(1))) void*)g,
                                     (__attribute__((address_space(3))) void*)l,
                                     16, 0, 0);
}

// ---------- merged fp32->bf16 convert: x (1048576 chunks) then Wo (262144) ----------
__global__ __launch_bounds__(256) void cvt_all(const float* __restrict__ x,
                                               const float* __restrict__ Wo,
                                               ushort* __restrict__ xb,
                                               ushort* __restrict__ Wob) {
    const int NX4 = (BB * SS * DD) / 4;
    int i = blockIdx.x * 256 + threadIdx.x;
    const float* src; ushort* dst; int j;
    if (i < NX4) { src = x; dst = xb; j = i; }
    else         { src = Wo; dst = Wob; j = i - NX4; }
    float4 v = ((const float4*)src)[j];
    ushort o[4] = { f2bf(v.x), f2bf(v.y), f2bf(v.z), f2bf(v.w) };
    ((uint2*)dst)[j] = *(const uint2*)o;
}

// ------- W cvt+transpose: fp32 [H][D][HD] -> bf16 W3T[(z*16+h)*64+e][d] -------
__global__ __launch_bounds__(256) void transpose_w3(const float* __restrict__ Wq,
                                                    const float* __restrict__ Wk,
                                                    const float* __restrict__ Wv,
                                                    ushort* __restrict__ W3T) {
    __shared__ ushort T[64][65];
    int z = blockIdx.z;
    const float* W = z == 0 ? Wq : (z == 1 ? Wk : Wv);
    int h = blockIdx.y, d0 = blockIdx.x * 64;
    const float* Wh = W + h * DD * HD;
    ushort* Wt = W3T + ((size_t)z * HH + h) * HD * DD;
    int t = threadIdx.x;
    #pragma unroll
    for (int i = 0; i < 4; i++) {
        int idx = t + i * 256;
        int d = idx >> 4, e4 = (idx & 15) * 4;
        float4 v = *(const float4*)(Wh + (d0 + d) * HD + e4);
        T[d][e4 + 0] = f2bf(v.x); T[d][e4 + 1] = f2bf(v.y);
        T[d][e4 + 2] = f2bf(v.z); T[d][e4 + 3] = f2bf(v.w);
    }
    __syncthreads();
    #pragma unroll
    for (int i = 0; i < 2; i++) {
        int idx = t + i * 256;
        int e = idx >> 3, d8 = (idx & 7) * 8;
        ushort tmp[8];
        #pragma unroll
        for (int j = 0; j < 8; j++) tmp[j] = T[d8 + j][e];
        *(uint4*)(Wt + e * DD + d0 + d8) = *(uint4*)tmp;
    }
}

// ---- QKV: xb[4096,1024] x W3T slice (NT, 128x128, global_load_lds). z=0: Q prescaled;
// ---- z=2: writes V transposed vT[(bh*64+e)][s] directly.
__global__ __launch_bounds__(256) void gemm_qkv(const ushort* __restrict__ xb,
                                                const ushort* __restrict__ W3T,
                                                const float* __restrict__ bq,
                                                const float* __restrict__ bk,
                                                const float* __restrict__ bv,
                                                ushort* __restrict__ qb,
                                                ushort* __restrict__ kb,
                                                ushort* __restrict__ vT) {
    __shared__ ushort Al[128 * 32];
    __shared__ ushort Bl[128 * 32];
    int z = blockIdx.z;
    const ushort* Wt   = W3T + (size_t)z * HH * HD * DD;
    const float*  bias = z == 0 ? bq : (z == 1 ? bk : bv);
    int m0 = blockIdx.x * 128, n0 = blockIdx.y * 128;
    int t = threadIdx.x, lane = t & 63, w = t >> 6;
    int wm = w & 1, wn = w >> 1;
    int qm = lane >> 4, lm = lane & 15;

    float4v acc[4][4] = {};
    for (int k0 = 0; k0 < DD; k0 += 32) {
        __syncthreads();
        #pragma unroll
        for (int r2 = 0; r2 < 2; r2++) {
            int c = t + r2 * 256;
            cp16(xb + (size_t)(m0 + (c >> 2)) * DD + k0 + (c & 3) * 8, Al + c * 8);
            cp16(Wt + (size_t)(n0 + (c >> 2)) * DD + k0 + (c & 3) * 8, Bl + c * 8);
        }
        __syncthreads();
        short8 a[4], b[4];
        #pragma unroll
        for (int i = 0; i < 4; i++)
            a[i] = *(const short8*)(Al + (wm * 64 + i * 16 + lm) * 32 + qm * 8);
        #pragma unroll
        for (int j = 0; j < 4; j++)
            b[j] = *(const short8*)(Bl + (wn * 64 + j * 16 + lm) * 32 + qm * 8);
        #pragma unroll
        for (int i = 0; i < 4; i++)
            #pragma unroll
            for (int j = 0; j < 4; j++)
                acc[i][j] = __builtin_amdgcn_mfma_f32_16x16x32_bf16(a[i], b[j], acc[i][j], 0, 0, 0);
    }
    if (z == 2) {
        #pragma unroll
        for (int j = 0; j < 4; j++) {
            int n = n0 + wn * 64 + j * 16 + lm;
            int h = n >> 6, e = n & 63;
            float bb = bias[n];
            #pragma unroll
            for (int i = 0; i < 4; i++) {
                int m = m0 + wm * 64 + i * 16 + qm * 4;
                int b_ = m >> 11, s = m & (SS - 1);
                ushort p4[4];
                #pragma unroll
                for (int r = 0; r < 4; r++) p4[r] = f2bf_f(acc[i][j][r] + bb);
                *(uint2*)(vT + ((size_t)(b_ * HH + h) * HD + e) * SS + s) = *(const uint2*)p4;
            }
        }
    } else {
        ushort* Out = z == 0 ? qb : kb;
        float sc = z == 0 ? QSCALE : 1.0f;
        #pragma unroll
        for (int j = 0; j < 4; j++) {
            int n = n0 + wn * 64 + j * 16 + lm;
            float bb = bias[n];
            #pragma unroll
            for (int i = 0; i < 4; i++)
                #pragma unroll
                for (int r = 0; r < 4; r++) {
                    int m = m0 + wm * 64 + i * 16 + qm * 4 + r;
                    Out[(size_t)m * DD + n] = f2bf_f((acc[i][j][r] + bb) * sc);
                }
        }
    }
}

// -------- flash attention (causal), S^T form. 512 threads, q-tile 128 (8 waves x 16q),
// -------- paired (qt, 15-qt). Each wave: St[64k][16q] -> in-lane softmax -> O[16q][64e].
__global__ __launch_bounds__(512) void attn(const ushort* __restrict__ Q,
                                            const ushort* __restrict__ K,
                                            const ushort* __restrict__ VT,
                                            ushort* __restrict__ O) {
    __shared__ ushort Ql[128][LSTR];
    __shared__ ushort Kl[2][64][LSTR];
    __shared__ ushort Vl[2][64][LSTR];
    __shared__ ushort Pl[8][16][LSTR];
    int px = blockIdx.x, bh = blockIdx.y;
    int b = bh >> 4, h = bh & 15;
    const ushort* Qp = Q + (size_t)b * SS * DD + h * HD;
    const ushort* Kp = K + (size_t)b * SS * DD + h * HD;
    const ushort* Vp = VT + (size_t)bh * HD * SS;
    int t = threadIdx.x, lane = t & 63, w = t >> 6;      // w in [0,8)
    int qm = lane >> 4, lm = lane & 15;
    int row0 = t >> 3, colc = (t & 7) * 8;               // staging: row0 in [0,64)

    #pragma unroll
    for (int ph = 0; ph < 2; ph++) {
        int qt = ph ? 15 - px : px;
        int m0 = qt * 128;
        int njt = 2 * (qt + 1);
        __syncthreads();   // prior phase fully done with all LDS
        *(uint4*)(&Ql[row0][colc])      = *(const uint4*)(Qp + (size_t)(m0 + row0) * DD + colc);
        *(uint4*)(&Ql[row0 + 64][colc]) = *(const uint4*)(Qp + (size_t)(m0 + row0 + 64) * DD + colc);
        *(uint4*)(&Kl[0][row0][colc])   = *(const uint4*)(Kp + (size_t)row0 * DD + colc);
        *(uint4*)(&Vl[0][row0][colc])   = *(const uint4*)(Vp + (size_t)row0 * SS + colc);

        float4v o[4] = {};
        float mi = -__builtin_inff(), li = 0.f;
        int cur = 0;
        int qg = m0 + w * 16 + lm;   // this lane's softmax q-row (global)

        for (int jt = 0; jt < njt; jt++) {
            __syncthreads();   // cur staged+visible; all waves done reading cur^1
            bool pre = jt + 1 < njt;
            uint4 pk, pv;
            if (pre) {
                int nn = (jt + 1) * 64;
                pk = *(const uint4*)(Kp + (size_t)(nn + row0) * DD + colc);
                pv = *(const uint4*)(Vp + (size_t)row0 * SS + nn + colc);
            }

            // St = K·Q^T: acc s[j] rows k=j*16+qm*4+r, col q=lm (q prescaled by QSCALE)
            float4v s[4] = {};
            #pragma unroll
            for (int kc = 0; kc < 2; kc++) {
                short8 bq8 = *(const short8*)(&Ql[w * 16 + lm][kc * 32 + qm * 8]);
                #pragma unroll
                for (int j = 0; j < 4; j++) {
                    short8 ak = *(const short8*)(&Kl[cur][j * 16 + lm][kc * 32 + qm * 8]);
                    s[j] = __builtin_amdgcn_mfma_f32_16x16x32_bf16(ak, bq8, s[j], 0, 0, 0);
                }
            }
            if (jt >= 2 * qt) {   // diagonal band: mask k > q
                #pragma unroll
                for (int j = 0; j < 4; j++)
                    #pragma unroll
                    for (int r = 0; r < 4; r++)
                        if (jt * 64 + j * 16 + qm * 4 + r > qg) s[j][r] = -__builtin_inff();
            }
            // in-lane softmax over 16 values (+2 shfl for cross-qm k-subsets)
            float mloc = s[0][0];
            #pragma unroll
            for (int j = 0; j < 4; j++)
                #pragma unroll
                for (int r = 0; r < 4; r++) mloc = fmaxf(mloc, s[j][r]);
            mloc = fmaxf(mloc, __shfl_xor(mloc, 16, 64));
            mloc = fmaxf(mloc, __shfl_xor(mloc, 32, 64));
            float mnew = fmaxf(mi, mloc);
            float sum = 0.f;
            #pragma unroll
            for (int j = 0; j < 4; j++)
                #pragma unroll
                for (int r = 0; r < 4; r++) {
                    float p = __builtin_amdgcn_exp2f(s[j][r] - mnew);
                    s[j][r] = p;
                    sum += p;
                }
            sum += __shfl_xor(sum, 16, 64);
            sum += __shfl_xor(sum, 32, 64);
            float alpha = __builtin_amdgcn_exp2f(mi - mnew);
            li = li * alpha + sum;
            mi = mnew;

            // P (bf16) -> Pl[q=lm][k], packed b64 writes
            #pragma unroll
            for (int j = 0; j < 4; j++) {
                ushort p4[4];
                #pragma unroll
                for (int r = 0; r < 4; r++) p4[r] = f2bf_f(s[j][r]);
                *(uint2*)(&Pl[w][lm][j * 16 + qm * 4]) = *(const uint2*)p4;
            }
            // rescale O (rows q = w*16+qm*4+r) with alpha gathered from lane qm*4+r
            #pragma unroll
            for (int r = 0; r < 4; r++) {
                float ar = __shfl(alpha, qm * 4 + r, 64);
                o[0][r] *= ar; o[1][r] *= ar; o[2][r] *= ar; o[3][r] *= ar;
            }
            asm volatile("s_waitcnt lgkmcnt(0)" ::: "memory");  // P writes visible (wave-internal)

            // O += P·V^T : A = Pl rows (b128), B = Vl rows (e x k)
            #pragma unroll
            for (int kc = 0; kc < 2; kc++) {
                short8 ap = *(const short8*)(&Pl[w][lm][kc * 32 + qm * 8]);
                #pragma unroll
                for (int jn = 0; jn < 4; jn++) {
                    short8 bv8 = *(const short8*)(&Vl[cur][jn * 16 + lm][kc * 32 + qm * 8]);
                    o[jn] = __builtin_amdgcn_mfma_f32_16x16x32_bf16(ap, bv8, o[jn], 0, 0, 0);
                }
            }
            if (pre) {
                *(uint4*)(&Kl[cur ^ 1][row0][colc]) = pk;
                *(uint4*)(&Vl[cur ^ 1][row0][colc]) = pv;
            }
            cur ^= 1;
        }
        // epilogue: O row q = m0 + w*16 + qm*4 + r, col e = jn*16+lm
        float lr[4];
        #pragma unroll
        for (int r = 0; r < 4; r++) lr[r] = __shfl(li, qm * 4 + r, 64);
        #pragma unroll
        for (int jn = 0; jn < 4; jn++)
            #pragma unroll
            for (int r = 0; r < 4; r++) {
                int sg = m0 + w * 16 + qm * 4 + r;
                O[((size_t)b * SS + sg) * DD + h * HD + jn * 16 + lm] = f2bf_f(o[jn][r] / lr[r]);
            }
    }
}

// ---- out proj: wvb[4096,1024] x Wob^T (NT, 128x64 tile, global_load_lds) -> fp32 ----
__global__ __launch_bounds__(256) void gemm_out(const ushort* __restrict__ X,
                                                const ushort* __restrict__ Wob,
                                                const float* __restrict__ bo,
                                                float* __restrict__ Out) {
    __shared__ ushort Al[128 * 32];
    __shared__ ushort Bl[64 * 32];
    int m0 = blockIdx.x * 128, n0 = blockIdx.y * 64;
    int t = threadIdx.x, lane = t & 63, w = t >> 6;
    int wm = w & 1, wn = w >> 1;
    int qm = lane >> 4, lm = lane & 15;

    float4v acc[4][2] = {};
    for (int k0 = 0; k0 < DD; k0 += 32) {
        __syncthreads();
        #pragma unroll
        for (int r2 = 0; r2 < 2; r2++) {
            int c = t + r2 * 256;
            cp16(X + (size_t)(m0 + (c >> 2)) * DD + k0 + (c & 3) * 8, Al + c * 8);
        }
        cp16(Wob + (size_t)(n0 + (t >> 2)) * DD + k0 + (t & 3) * 8, Bl + t * 8);
        __syncthreads();
        short8 a[4], b[2];
        #pragma unroll
        for (int i = 0; i < 4; i++)
            a[i] = *(const short8*)(Al + (wm * 64 + i * 16 + lm) * 32 + qm * 8);
        #pragma unroll
        for (int j = 0; j < 2; j++)
            b[j] = *(const short8*)(Bl + (wn * 32 + j * 16 + lm) * 32 + qm * 8);
        #pragma unroll
        for (int i = 0; i < 4; i++)
            #pragma unroll
            for (int j = 0; j < 2; j++)
                acc[i][j] = __builtin_amdgcn_mfma_f32_16x16x32_bf16(a[i], b[j], acc[i][j], 0, 0, 0);
    }
    #pragma unroll
    for (int j = 0; j < 2; j++) {
        int n = n0 + wn * 32 + j * 16 + lm;
        float bb = bo[n];
        #pragma unroll
        for (int i = 0; i < 4; i++)
            #pragma unroll
            for (int r = 0; r < 4; r++) {
                int m = m0 + wm * 64 + i * 16 + qm * 4 + r;
                Out[(size_t)m * DD + n] = acc[i][j][r] + bb;
            }
    }
}

extern "C" void kernel_launch(void* const* d_in, const int* in_sizes, int n_in,
                              void* d_out, int out_size, void* d_ws, size_t ws_size,
                              hipStream_t stream) {
    const float* x   = (const float*)d_in[0];
    const float* Wq  = (const float*)d_in[1];
    const float* bq  = (const float*)d_in[2];
    const float* Wk  = (const float*)d_in[3];
    const float* bk  = (const float*)d_in[4];
    const float* Wv_ = (const float*)d_in[5];
    const float* bv  = (const float*)d_in[6];
    const float* Wo  = (const float*)d_in[7];
    const float* bo  = (const float*)d_in[8];
    float* out = (float*)d_out;

    ushort* xb  = (ushort*)d_ws;
    ushort* W3T = xb  + (size_t)BB * SS * DD;
    ushort* Wob = W3T + (size_t)3 * HH * HD * DD;
    ushort* qb  = Wob + (size_t)DD * DD;
    ushort* kb  = qb + (size_t)BB * SS * DD;
    ushort* vT  = kb + (size_t)BB * SS * DD;
    ushort* wvb = vT + (size_t)BB * SS * DD;

    cvt_all<<<dim3(5120), 256, 0, stream>>>(x, Wo, xb, Wob);
    transpose_w3<<<dim3(16, 16, 3), 256, 0, stream>>>(Wq, Wk, Wv_, W3T);
    gemm_qkv<<<dim3(32, 8, 3), 256, 0, stream>>>(xb, W3T, bq, bk, bv, qb, kb, vT);
    attn<<<dim3(8, 32), 512, 0, stream>>>(qb, kb, vT, wvb);
    gemm_out<<<dim3(32, 16), 256, 0, stream>>>(wvb, Wob, bo, out);
}